// Round 2
// baseline (5399.833 us; speedup 1.0000x reference)
//
#include <hip/hip_runtime.h>

// GroupQLinear: dequant(int8 group-quant) -> GEMM -> bias -> group requant.
// e = floor(log2(absmax/gmax)) is DISCRETE: y must track the true value to
// ~<1e-6 relative or groups flip exponent (error 63 observed with f32 accum).
// => LDS tiles in f32 (dq_A matches jax f32 bit-exactly), f64 FMA accumulate.

#define TM 128
#define TN 128
#define TK 16
#define LDT 132  // padded LDS leading dim

__global__ __launch_bounds__(256, 2) void gemm_dq_kernel(
    const int* __restrict__ xq, const float* __restrict__ xdelta,
    const int* __restrict__ xe, const float* __restrict__ W,
    const float* __restrict__ bias, float* __restrict__ y,
    int M, int N, int K)
{
    __shared__ float As[TK][LDT];   // As[k][m], A dequantized (f32, matches jax dq)
    __shared__ float Bs[TK][LDT];   // Bs[k][n]

    const int tid = threadIdx.x;
    const int tx = tid & 15;
    const int ty = tid >> 4;
    const int m0 = blockIdx.y * TM;
    const int n0 = blockIdx.x * TN;

    // staging: each thread loads 8 contiguous elements of one row
    const int srow = tid >> 1;          // 0..127
    const int scol = (tid & 1) * 8;     // 0 or 8
    const int Kg = K >> 5;

    const int*   aptr = xq + (size_t)(m0 + srow) * K + scol;
    const float* bptr = W  + (size_t)(n0 + srow) * K + scol;
    const float  adelta = xdelta[m0 + srow];
    const int*   aeptr  = xe + (size_t)(m0 + srow) * Kg;

    int4 pa0, pa1; float4 pb0, pb1; float pscale;

    pa0 = *(const int4*)(aptr);
    pa1 = *(const int4*)(aptr + 4);
    pb0 = *(const float4*)(bptr);
    pb1 = *(const float4*)(bptr + 4);
    pscale = adelta * exp2f(-(float)aeptr[scol >> 5]);

    double acc[8][8];
#pragma unroll
    for (int i = 0; i < 8; ++i)
#pragma unroll
        for (int j = 0; j < 8; ++j) acc[i][j] = 0.0;

    for (int kt = 0; kt < K; kt += TK) {
        {
            float* as = &As[scol][srow];
            as[0*LDT] = (float)pa0.x * pscale;
            as[1*LDT] = (float)pa0.y * pscale;
            as[2*LDT] = (float)pa0.z * pscale;
            as[3*LDT] = (float)pa0.w * pscale;
            as[4*LDT] = (float)pa1.x * pscale;
            as[5*LDT] = (float)pa1.y * pscale;
            as[6*LDT] = (float)pa1.z * pscale;
            as[7*LDT] = (float)pa1.w * pscale;
            float* bs = &Bs[scol][srow];
            bs[0*LDT] = pb0.x;
            bs[1*LDT] = pb0.y;
            bs[2*LDT] = pb0.z;
            bs[3*LDT] = pb0.w;
            bs[4*LDT] = pb1.x;
            bs[5*LDT] = pb1.y;
            bs[6*LDT] = pb1.z;
            bs[7*LDT] = pb1.w;
        }
        __syncthreads();

        if (kt + TK < K) {
            const int k1 = kt + TK;
            pa0 = *(const int4*)(aptr + k1);
            pa1 = *(const int4*)(aptr + k1 + 4);
            pb0 = *(const float4*)(bptr + k1);
            pb1 = *(const float4*)(bptr + k1 + 4);
            pscale = adelta * exp2f(-(float)aeptr[(k1 + scol) >> 5]);
        }

#pragma unroll
        for (int kk = 0; kk < TK; ++kk) {
            const float4 a0 = *(const float4*)&As[kk][ty * 4];
            const float4 a1 = *(const float4*)&As[kk][64 + ty * 4];
            const float4 b0 = *(const float4*)&Bs[kk][tx * 4];
            const float4 b1 = *(const float4*)&Bs[kk][64 + tx * 4];
            const double ad[8] = {(double)a0.x, (double)a0.y, (double)a0.z, (double)a0.w,
                                  (double)a1.x, (double)a1.y, (double)a1.z, (double)a1.w};
            const double bd[8] = {(double)b0.x, (double)b0.y, (double)b0.z, (double)b0.w,
                                  (double)b1.x, (double)b1.y, (double)b1.z, (double)b1.w};
#pragma unroll
            for (int i = 0; i < 8; ++i)
#pragma unroll
                for (int j = 0; j < 8; ++j)
                    acc[i][j] = fma(ad[i], bd[j], acc[i][j]);
        }
        __syncthreads();
    }

    // epilogue: add bias (f64), round to f32, write y to d_out q-section
    const float4 bb0 = *(const float4*)&bias[n0 + tx * 4];
    const float4 bb1 = *(const float4*)&bias[n0 + 64 + tx * 4];
#pragma unroll
    for (int i = 0; i < 8; ++i) {
        const int row = m0 + ((i < 4) ? (ty * 4 + i) : (64 + ty * 4 + (i - 4)));
        float4 v0, v1;
        v0.x = (float)(acc[i][0] + (double)bb0.x);
        v0.y = (float)(acc[i][1] + (double)bb0.y);
        v0.z = (float)(acc[i][2] + (double)bb0.z);
        v0.w = (float)(acc[i][3] + (double)bb0.w);
        v1.x = (float)(acc[i][4] + (double)bb1.x);
        v1.y = (float)(acc[i][5] + (double)bb1.y);
        v1.z = (float)(acc[i][6] + (double)bb1.z);
        v1.w = (float)(acc[i][7] + (double)bb1.w);
        *(float4*)&y[(size_t)row * N + n0 + tx * 4] = v0;
        *(float4*)&y[(size_t)row * N + n0 + 64 + tx * 4] = v1;
    }
}

// One block per token row (N=4096, 256 threads, 16 elems/thread).
// Re-quantizes y in place (q section of d_out) and writes delta / e sections.
__global__ __launch_bounds__(256) void requant_kernel(
    float* __restrict__ y, float* __restrict__ odelta,
    float* __restrict__ oe, int N)
{
    const int t = blockIdx.x;
    const int tid = threadIdx.x;
    float* row = y + (size_t)t * N;

    float4 v[4];
    float cmax[4];
    float amax = 0.f;
#pragma unroll
    for (int j = 0; j < 4; ++j) {
        v[j] = *(const float4*)&row[(tid + j * 256) * 4];
        const float m01 = fmaxf(fabsf(v[j].x), fabsf(v[j].y));
        const float m23 = fmaxf(fabsf(v[j].z), fabsf(v[j].w));
        cmax[j] = fmaxf(m01, m23);
        amax = fmaxf(amax, cmax[j]);
    }

    __shared__ float red[256];
    red[tid] = amax;
    __syncthreads();
#pragma unroll
    for (int s = 128; s >= 1; s >>= 1) {
        if (tid < s) red[tid] = fmaxf(red[tid], red[tid + s]);
        __syncthreads();
    }
    const float absmax = red[0];
    const float delta = absmax / 127.0f;
    if (tid == 0) odelta[t] = delta;

    const int G = N >> 5;  // 128 groups
#pragma unroll
    for (int j = 0; j < 4; ++j) {
        // chunk c = tid + j*256 covers elements [4c,4c+4) -> group (tid>>3) + 32j
        float gm = cmax[j];
        gm = fmaxf(gm, __shfl_xor(gm, 1));
        gm = fmaxf(gm, __shfl_xor(gm, 2));
        gm = fmaxf(gm, __shfl_xor(gm, 4));
        const float ratio = (delta * 127.0f) / fmaxf(gm, 1e-8f);
        const float rr = fmaxf(ratio, 1.0f);
        float e = floorf(log2f(rr));
        e = fminf(e, 15.0f);
        const float scale = delta * exp2f(-e);
        if ((tid & 7) == 0) oe[(size_t)t * G + (tid >> 3) + 32 * j] = e;

        const float den = fmaxf(scale, 1e-8f);
        float4 q;
        q.x = fminf(fmaxf(rintf(v[j].x / den), -127.f), 127.f);
        q.y = fminf(fmaxf(rintf(v[j].y / den), -127.f), 127.f);
        q.z = fminf(fmaxf(rintf(v[j].z / den), -127.f), 127.f);
        q.w = fminf(fmaxf(rintf(v[j].w / den), -127.f), 127.f);
        *(float4*)&row[(tid + j * 256) * 4] = q;
    }
}

extern "C" void kernel_launch(void* const* d_in, const int* in_sizes, int n_in,
                              void* d_out, int out_size, void* d_ws, size_t ws_size,
                              hipStream_t stream) {
    const int*   xq     = (const int*)d_in[0];
    const float* xdelta = (const float*)d_in[1];
    const int*   xe     = (const int*)d_in[2];
    const float* W      = (const float*)d_in[3];
    const float* bias   = (const float*)d_in[4];

    const int M = in_sizes[1];            // B*T = 8192
    const int K = in_sizes[0] / M;        // H = 4096
    const int N = in_sizes[4];            // O = 4096

    float* out    = (float*)d_out;
    float* yq     = out;                          // M*N  (holds f32 y, then q)
    float* odelta = out + (size_t)M * N;          // M
    float* oe     = odelta + M;                   // M*(N/32)

    dim3 grid(N / TN, M / TM);
    gemm_dq_kernel<<<grid, dim3(256), 0, stream>>>(xq, xdelta, xe, W, bias, yq, M, N, K);
    requant_kernel<<<dim3(M), dim3(256), 0, stream>>>(yq, odelta, oe, N);
}

// Round 3
// 1480.268 us; speedup vs baseline: 3.6479x; 3.6479x over previous
//
#include <hip/hip_runtime.h>

// GroupQLinear: dequant(int8 group-quant) -> GEMM -> bias -> group requant.
// e = floor(log2(absmax/gmax)) is DISCRETE -> y must be ~1e-7-accurate.
// Scheme: y/delta_m = sum_g 2^-e(m,g) * IntDot_g(q, W16) * 2^(E_o-14)
//                    + sum_k (q*2^-e)[bf16 exact] * (lo0+lo1)[bf16 residual]
// IntDot via v_mfma_i32_32x32x32_i8 (exact i32, one group per MFMA),
// residual via v_mfma_f32_32x32x16_bf16 (f32 acc OK: residuals are 2^-16 scale).

typedef __attribute__((ext_vector_type(4)))  int    int32x4;
typedef __attribute__((ext_vector_type(16))) int    int32x16;
typedef __attribute__((ext_vector_type(8)))  short  short8;
typedef __attribute__((ext_vector_type(16))) float  f32x16;

__device__ __forceinline__ ushort f2bf(float x) {
    unsigned u = __float_as_uint(x);
    unsigned r = (u + 0x7FFFu + ((u >> 16) & 1u)) >> 16;  // RN-even
    return (ushort)r;
}
__device__ __forceinline__ float bf2f(ushort h) {
    return __uint_as_float(((unsigned)h) << 16);
}

// ---------------- prep kernels ----------------

__global__ __launch_bounds__(256) void wprep_rowmax(const float* __restrict__ W,
                                                    int* __restrict__ Eexp, int K) {
    const int o = blockIdx.x;
    const float* row = W + (size_t)o * K;
    float m = 0.f;
    for (int k = threadIdx.x; k < K; k += 256) m = fmaxf(m, fabsf(row[k]));
    __shared__ float red[256];
    red[threadIdx.x] = m;
    __syncthreads();
    for (int s = 128; s >= 1; s >>= 1) {
        if (threadIdx.x < s) red[threadIdx.x] = fmaxf(red[threadIdx.x], red[threadIdx.x + s]);
        __syncthreads();
    }
    if (threadIdx.x == 0) Eexp[o] = ilogbf(red[0]);   // floor(log2(rowmax)), rowmax>0
}

__global__ __launch_bounds__(256) void wprep_slice(const float* __restrict__ W,
                                                   const int* __restrict__ Eexp,
                                                   signed char* __restrict__ d0p,
                                                   signed char* __restrict__ d1p,
                                                   ushort* __restrict__ l0p,
                                                   ushort* __restrict__ l1p, int K) {
    const int o = blockIdx.x;
    const int E = Eexp[o];
    const float s  = ldexpf(1.0f, 14 - E);
    const float si = ldexpf(1.0f, E - 14);
    const float* row = W + (size_t)o * K;
    signed char* d0r = d0p + (size_t)o * K;
    signed char* d1r = d1p + (size_t)o * K;
    ushort* l0r = l0p + (size_t)o * K;
    ushort* l1r = l1p + (size_t)o * K;
    for (int k = threadIdx.x * 4; k < K; k += 1024) {
        float4 w = *(const float4*)&row[k];
        float wv[4] = {w.x, w.y, w.z, w.w};
        char  q0[4], q1[4];
        ushort h0[4], h1[4];
#pragma unroll
        for (int i = 0; i < 4; ++i) {
            float W16f = rintf(wv[i] * s);
            W16f = fminf(fmaxf(W16f, -32512.f), 32512.f);
            int W16 = (int)W16f;
            int D0 = (W16 + 128) >> 8;           // balanced digits: |D0|<=127
            int D1 = W16 - (D0 << 8);            // in [-128,127]
            float r0 = fmaf(-W16f, si, wv[i]);   // residual, exact to ~ulp
            ushort L0 = f2bf(r0);
            float r1 = r0 - bf2f(L0);            // Sterbenz-exact
            ushort L1 = f2bf(r1);
            q0[i] = (char)D0; q1[i] = (char)D1; h0[i] = L0; h1[i] = L1;
        }
        *(int*)&d0r[k] = (q0[0] & 0xFF) | ((q0[1] & 0xFF) << 8) | ((q0[2] & 0xFF) << 16) | (q0[3] << 24);
        *(int*)&d1r[k] = (q1[0] & 0xFF) | ((q1[1] & 0xFF) << 8) | ((q1[2] & 0xFF) << 16) | (q1[3] << 24);
        *(ushort4*)&l0r[k] = make_ushort4(h0[0], h0[1], h0[2], h0[3]);
        *(ushort4*)&l1r[k] = make_ushort4(h1[0], h1[1], h1[2], h1[3]);
    }
}

__global__ __launch_bounds__(256) void xprep(const int* __restrict__ xq,
                                             signed char* __restrict__ q8, int K) {
    const int m = blockIdx.x;
    const int* row = xq + (size_t)m * K;
    signed char* out = q8 + (size_t)m * K;
    for (int k = threadIdx.x * 4; k < K; k += 1024) {
        int4 v = *(const int4*)&row[k];
        *(int*)&out[k] = (v.x & 0xFF) | ((v.y & 0xFF) << 8) | ((v.z & 0xFF) << 16) | (v.w << 24);
    }
}

// ---------------- Ozaki GEMM ----------------
// block: 512 thr = 8 waves (2 o-dir x 4 m-dir); block tile 128m x 128o; BK=32 (1 group).
// wave tile: 64o x 32m = 2 sub-tiles of 32x32.  D[i=o, j=m] (col=lane&31=m).
// LDS frag-contiguous layout: byte = OFF + kb*2048 + row*16 (+sub), kb = k-block of 16B.

#define OFF_Q  0        // i8  [128 m][32 k]   4096 B
#define OFF_D0 4096     // i8  [128 o][32 k]   4096
#define OFF_D1 8192     // i8                  4096
#define OFF_AP 12288    // bf16[128 m][32 k]   8192
#define OFF_L0 20480    // bf16[128 o][32 k]   8192
#define OFF_L1 28672    // bf16                8192
#define OFF_E  36864    // f32 [128 m]          512
#define SMEM_SZ 37376

__global__ __launch_bounds__(512, 1) void gemm_ozaki(
    const signed char* __restrict__ q8,   // [M][K]
    const int* __restrict__ xe,           // [M][K/32]
    const float* __restrict__ xdelta,     // [M]
    const signed char* __restrict__ d0p,  // [N][K]
    const signed char* __restrict__ d1p,
    const ushort* __restrict__ l0p,       // bf16 [N][K]
    const ushort* __restrict__ l1p,
    const int* __restrict__ Eexp,         // [N]
    const float* __restrict__ bias,       // [N]
    float* __restrict__ y,                // [M][N] f32
    int M, int N, int K)
{
    __shared__ alignas(16) char smem[SMEM_SZ];

    const int tid = threadIdx.x;
    const int m0 = blockIdx.y * 128;
    const int n0 = blockIdx.x * 128;
    const int Kg = K >> 5;

    // staging ids
    const int rr = tid >> 2;            // 0..127
    const int kp = (tid & 3) * 8;       // 0,8,16,24
    // mfma ids
    const int w = tid >> 6, lane = tid & 63, lj = lane & 31, hi = lane >> 5;
    const int o_w = (w & 1) * 64, m_w = (w >> 1) * 32;

    double yaccE[2][16];
    f32x16 racc[2];
#pragma unroll
    for (int s = 0; s < 2; ++s) {
#pragma unroll
        for (int r = 0; r < 16; ++r) { yaccE[s][r] = 0.0; racc[s][r] = 0.f; }
    }
    int32x16 zi;
#pragma unroll
    for (int i = 0; i < 16; ++i) zi[i] = 0;

    // prefetch tile kt=0
    long pq, pd0, pd1; short8 pl0, pl1; int pe;
    {
        const size_t qoff = (size_t)(m0 + rr) * K + kp;
        const size_t woff = (size_t)(n0 + rr) * K + kp;
        pq  = *(const long*)(q8 + qoff);
        pe  = xe[(size_t)(m0 + rr) * Kg];
        pd0 = *(const long*)(d0p + woff);
        pd1 = *(const long*)(d1p + woff);
        pl0 = *(const short8*)(l0p + woff);
        pl1 = *(const short8*)(l1p + woff);
    }

    for (int kt = 0; kt < K; kt += 32) {
        __syncthreads();   // previous compute done; LDS free
        // stage registers -> LDS
        {
            const float es = ldexpf(1.0f, -pe);
            if (kp == 0) *(float*)(smem + OFF_E + rr * 4) = es;
            *(long*)(smem + OFF_Q  + (kp >> 4) * 2048 + rr * 16 + (kp & 15)) = pq;
            *(long*)(smem + OFF_D0 + (kp >> 4) * 2048 + rr * 16 + (kp & 15)) = pd0;
            *(long*)(smem + OFF_D1 + (kp >> 4) * 2048 + rr * 16 + (kp & 15)) = pd1;
            short8 ap;
#pragma unroll
            for (int i = 0; i < 8; ++i) {
                signed char qq = (signed char)(pq >> (8 * i));
                ap[i] = (short)f2bf((float)qq * es);    // exact: q*2^-e fits bf16
            }
            *(short8*)(smem + OFF_AP + (kp >> 3) * 2048 + rr * 16) = ap;
            *(short8*)(smem + OFF_L0 + (kp >> 3) * 2048 + rr * 16) = pl0;
            *(short8*)(smem + OFF_L1 + (kp >> 3) * 2048 + rr * 16) = pl1;
        }
        // prefetch next tile (completes under compute)
        if (kt + 32 < K) {
            const int kn = kt + 32;
            const size_t qoff = (size_t)(m0 + rr) * K + kn + kp;
            const size_t woff = (size_t)(n0 + rr) * K + kn + kp;
            pq  = *(const long*)(q8 + qoff);
            pe  = xe[(size_t)(m0 + rr) * Kg + (kn >> 5)];
            pd0 = *(const long*)(d0p + woff);
            pd1 = *(const long*)(d1p + woff);
            pl0 = *(const short8*)(l0p + woff);
            pl1 = *(const short8*)(l1p + woff);
        }
        __syncthreads();   // LDS ready
        // compute
        {
            const int mrow = m_w + lj;
            int32x4 qf  = *(const int32x4*)(smem + OFF_Q + hi * 2048 + mrow * 16);
            short8  ap0 = *(const short8*)(smem + OFF_AP + (0 + hi) * 2048 + mrow * 16);
            short8  ap1 = *(const short8*)(smem + OFF_AP + (2 + hi) * 2048 + mrow * 16);
            const double esd = (double)*(const float*)(smem + OFF_E + mrow * 4);
#pragma unroll
            for (int s = 0; s < 2; ++s) {
                const int orow = o_w + 32 * s + lj;
                int32x4 a0 = *(const int32x4*)(smem + OFF_D0 + hi * 2048 + orow * 16);
                int32x4 a1 = *(const int32x4*)(smem + OFF_D1 + hi * 2048 + orow * 16);
                int32x16 S0 = __builtin_amdgcn_mfma_i32_32x32x32_i8(a0, qf, zi, 0, 0, 0);
                int32x16 S1 = __builtin_amdgcn_mfma_i32_32x32x32_i8(a1, qf, zi, 0, 0, 0);
                short8 l00 = *(const short8*)(smem + OFF_L0 + (0 + hi) * 2048 + orow * 16);
                short8 l01 = *(const short8*)(smem + OFF_L0 + (2 + hi) * 2048 + orow * 16);
                short8 l10 = *(const short8*)(smem + OFF_L1 + (0 + hi) * 2048 + orow * 16);
                short8 l11 = *(const short8*)(smem + OFF_L1 + (2 + hi) * 2048 + orow * 16);
                racc[s] = __builtin_amdgcn_mfma_f32_32x32x16_bf16(l00, ap0, racc[s], 0, 0, 0);
                racc[s] = __builtin_amdgcn_mfma_f32_32x32x16_bf16(l01, ap1, racc[s], 0, 0, 0);
                racc[s] = __builtin_amdgcn_mfma_f32_32x32x16_bf16(l10, ap0, racc[s], 0, 0, 0);
                racc[s] = __builtin_amdgcn_mfma_f32_32x32x16_bf16(l11, ap1, racc[s], 0, 0, 0);
#pragma unroll
                for (int r = 0; r < 16; ++r) {
                    const int c01 = (S0[r] << 8) + S1[r];   // exact, |.| < 2^28
                    yaccE[s][r] = fma((double)c01, esd, yaccE[s][r]);
                }
            }
        }
    }

    // epilogue: scale, transpose via LDS (per-wave region), coalesced store
    __syncthreads();
    const double delta_d = (double)xdelta[m0 + m_w + lj];
    float* tw = (float*)(void*)smem + w * 1056;   // 32x33 f32 per wave
#pragma unroll
    for (int s = 0; s < 2; ++s) {
#pragma unroll
        for (int r = 0; r < 16; ++r) {
            const int i = (r & 3) + 8 * (r >> 2) + 4 * hi;   // o_local
            const int o = n0 + o_w + 32 * s + i;
            double v = ldexp(yaccE[s][r], Eexp[o] - 14);
            v = (v + (double)racc[s][r]) * delta_d + (double)bias[o];
            tw[i * 33 + lj] = (float)v;
        }
        __syncthreads();
#pragma unroll
        for (int it = 0; it < 16; ++it) {
            const int mr = 2 * it + hi;
            y[(size_t)(m0 + m_w + mr) * N + (n0 + o_w + 32 * s + lj)] = tw[lj * 33 + mr];
        }
        __syncthreads();
    }
}

// ---------------- fallback f64 GEMM (known-good, r2) ----------------

#define TM 128
#define TN 128
#define TK 16
#define LDT 132

__global__ __launch_bounds__(256, 2) void gemm_dq_kernel(
    const int* __restrict__ xq, const float* __restrict__ xdelta,
    const int* __restrict__ xe, const float* __restrict__ W,
    const float* __restrict__ bias, float* __restrict__ y,
    int M, int N, int K)
{
    __shared__ float As[TK][LDT];
    __shared__ float Bs[TK][LDT];
    const int tid = threadIdx.x;
    const int tx = tid & 15;
    const int ty = tid >> 4;
    const int m0 = blockIdx.y * TM;
    const int n0 = blockIdx.x * TN;
    const int srow = tid >> 1;
    const int scol = (tid & 1) * 8;
    const int Kg = K >> 5;
    const int*   aptr = xq + (size_t)(m0 + srow) * K + scol;
    const float* bptr = W  + (size_t)(n0 + srow) * K + scol;
    const float  adelta = xdelta[m0 + srow];
    const int*   aeptr  = xe + (size_t)(m0 + srow) * Kg;
    int4 pa0, pa1; float4 pb0, pb1; float pscale;
    pa0 = *(const int4*)(aptr);
    pa1 = *(const int4*)(aptr + 4);
    pb0 = *(const float4*)(bptr);
    pb1 = *(const float4*)(bptr + 4);
    pscale = adelta * exp2f(-(float)aeptr[scol >> 5]);
    double acc[8][8];
#pragma unroll
    for (int i = 0; i < 8; ++i)
#pragma unroll
        for (int j = 0; j < 8; ++j) acc[i][j] = 0.0;
    for (int kt = 0; kt < K; kt += TK) {
        {
            float* as = &As[scol][srow];
            as[0*LDT] = (float)pa0.x * pscale; as[1*LDT] = (float)pa0.y * pscale;
            as[2*LDT] = (float)pa0.z * pscale; as[3*LDT] = (float)pa0.w * pscale;
            as[4*LDT] = (float)pa1.x * pscale; as[5*LDT] = (float)pa1.y * pscale;
            as[6*LDT] = (float)pa1.z * pscale; as[7*LDT] = (float)pa1.w * pscale;
            float* bs = &Bs[scol][srow];
            bs[0*LDT] = pb0.x; bs[1*LDT] = pb0.y; bs[2*LDT] = pb0.z; bs[3*LDT] = pb0.w;
            bs[4*LDT] = pb1.x; bs[5*LDT] = pb1.y; bs[6*LDT] = pb1.z; bs[7*LDT] = pb1.w;
        }
        __syncthreads();
        if (kt + TK < K) {
            const int k1 = kt + TK;
            pa0 = *(const int4*)(aptr + k1);
            pa1 = *(const int4*)(aptr + k1 + 4);
            pb0 = *(const float4*)(bptr + k1);
            pb1 = *(const float4*)(bptr + k1 + 4);
            pscale = adelta * exp2f(-(float)aeptr[(k1 + scol) >> 5]);
        }
#pragma unroll
        for (int kk = 0; kk < TK; ++kk) {
            const float4 a0 = *(const float4*)&As[kk][ty * 4];
            const float4 a1 = *(const float4*)&As[kk][64 + ty * 4];
            const float4 b0 = *(const float4*)&Bs[kk][tx * 4];
            const float4 b1 = *(const float4*)&Bs[kk][64 + tx * 4];
            const double ad[8] = {(double)a0.x, (double)a0.y, (double)a0.z, (double)a0.w,
                                  (double)a1.x, (double)a1.y, (double)a1.z, (double)a1.w};
            const double bd[8] = {(double)b0.x, (double)b0.y, (double)b0.z, (double)b0.w,
                                  (double)b1.x, (double)b1.y, (double)b1.z, (double)b1.w};
#pragma unroll
            for (int i = 0; i < 8; ++i)
#pragma unroll
                for (int j = 0; j < 8; ++j)
                    acc[i][j] = fma(ad[i], bd[j], acc[i][j]);
        }
        __syncthreads();
    }
    const float4 bb0 = *(const float4*)&bias[n0 + tx * 4];
    const float4 bb1 = *(const float4*)&bias[n0 + 64 + tx * 4];
#pragma unroll
    for (int i = 0; i < 8; ++i) {
        const int row = m0 + ((i < 4) ? (ty * 4 + i) : (64 + ty * 4 + (i - 4)));
        float4 v0, v1;
        v0.x = (float)(acc[i][0] + (double)bb0.x); v0.y = (float)(acc[i][1] + (double)bb0.y);
        v0.z = (float)(acc[i][2] + (double)bb0.z); v0.w = (float)(acc[i][3] + (double)bb0.w);
        v1.x = (float)(acc[i][4] + (double)bb1.x); v1.y = (float)(acc[i][5] + (double)bb1.y);
        v1.z = (float)(acc[i][6] + (double)bb1.z); v1.w = (float)(acc[i][7] + (double)bb1.w);
        *(float4*)&y[(size_t)row * N + n0 + tx * 4] = v0;
        *(float4*)&y[(size_t)row * N + n0 + 64 + tx * 4] = v1;
    }
}

// ---------------- requant (unchanged, known-good) ----------------

__global__ __launch_bounds__(256) void requant_kernel(
    float* __restrict__ y, float* __restrict__ odelta,
    float* __restrict__ oe, int N)
{
    const int t = blockIdx.x;
    const int tid = threadIdx.x;
    float* row = y + (size_t)t * N;
    float4 v[4];
    float cmax[4];
    float amax = 0.f;
#pragma unroll
    for (int j = 0; j < 4; ++j) {
        v[j] = *(const float4*)&row[(tid + j * 256) * 4];
        const float m01 = fmaxf(fabsf(v[j].x), fabsf(v[j].y));
        const float m23 = fmaxf(fabsf(v[j].z), fabsf(v[j].w));
        cmax[j] = fmaxf(m01, m23);
        amax = fmaxf(amax, cmax[j]);
    }
    __shared__ float red[256];
    red[tid] = amax;
    __syncthreads();
#pragma unroll
    for (int s = 128; s >= 1; s >>= 1) {
        if (tid < s) red[tid] = fmaxf(red[tid], red[tid + s]);
        __syncthreads();
    }
    const float absmax = red[0];
    const float delta = absmax / 127.0f;
    if (tid == 0) odelta[t] = delta;
    const int G = N >> 5;
#pragma unroll
    for (int j = 0; j < 4; ++j) {
        float gm = cmax[j];
        gm = fmaxf(gm, __shfl_xor(gm, 1));
        gm = fmaxf(gm, __shfl_xor(gm, 2));
        gm = fmaxf(gm, __shfl_xor(gm, 4));
        const float ratio = (delta * 127.0f) / fmaxf(gm, 1e-8f);
        const float rr = fmaxf(ratio, 1.0f);
        float e = floorf(log2f(rr));
        e = fminf(e, 15.0f);
        const float scale = delta * exp2f(-e);
        if ((tid & 7) == 0) oe[(size_t)t * G + (tid >> 3) + 32 * j] = e;
        const float den = fmaxf(scale, 1e-8f);
        float4 q;
        q.x = fminf(fmaxf(rintf(v[j].x / den), -127.f), 127.f);
        q.y = fminf(fmaxf(rintf(v[j].y / den), -127.f), 127.f);
        q.z = fminf(fmaxf(rintf(v[j].z / den), -127.f), 127.f);
        q.w = fminf(fmaxf(rintf(v[j].w / den), -127.f), 127.f);
        *(float4*)&row[(tid + j * 256) * 4] = q;
    }
}

// ---------------- launch ----------------

extern "C" void kernel_launch(void* const* d_in, const int* in_sizes, int n_in,
                              void* d_out, int out_size, void* d_ws, size_t ws_size,
                              hipStream_t stream) {
    const int*   xq     = (const int*)d_in[0];
    const float* xdelta = (const float*)d_in[1];
    const int*   xe     = (const int*)d_in[2];
    const float* W      = (const float*)d_in[3];
    const float* bias   = (const float*)d_in[4];

    const int M = in_sizes[1];            // 8192
    const int K = in_sizes[0] / M;        // 4096
    const int N = in_sizes[4];            // 4096

    float* out    = (float*)d_out;
    float* yq     = out;                  // holds f32 y, then q in-place
    float* odelta = out + (size_t)M * N;
    float* oe     = odelta + M;

    const size_t szNK = (size_t)N * K;
    const size_t szMK = (size_t)M * K;
    const size_t need = 6 * szNK + szMK + 4 * (size_t)N;

    if (ws_size >= need) {
        char* ws = (char*)d_ws;
        signed char* d0p = (signed char*)ws;
        signed char* d1p = (signed char*)(ws + szNK);
        ushort*      l0p = (ushort*)(ws + 2 * szNK);
        ushort*      l1p = (ushort*)(ws + 4 * szNK);
        signed char* q8  = (signed char*)(ws + 6 * szNK);
        int*         Ee  = (int*)(ws + 6 * szNK + szMK);

        wprep_rowmax<<<dim3(N), dim3(256), 0, stream>>>(W, Ee, K);
        wprep_slice<<<dim3(N), dim3(256), 0, stream>>>(W, Ee, d0p, d1p, l0p, l1p, K);
        xprep<<<dim3(M), dim3(256), 0, stream>>>(xq, q8, K);
        gemm_ozaki<<<dim3(N / 128, M / 128), dim3(512), 0, stream>>>(
            q8, xe, xdelta, d0p, d1p, l0p, l1p, Ee, bias, yq, M, N, K);
    } else {
        gemm_dq_kernel<<<dim3(N / TN, M / TM), dim3(256), 0, stream>>>(
            xq, xdelta, xe, W, bias, yq, M, N, K);
    }
    requant_kernel<<<dim3(M), dim3(256), 0, stream>>>(yq, odelta, oe, N);
}